// Round 18
// baseline (1031.522 us; speedup 1.0000x reference)
//
#include <hip/hip_runtime.h>

// ---------------------------------------------------------------------------
// MRT12 v18: head GEMM moves to the high-occupancy quadrant: 128x128 tile,
// 4 waves (64x64/wave), BK=32, 32KB LDS dbuf, launch_bounds(256,4) ->
// ~4 blocks/CU (16 waves/CU) for m114 cross-block overlap — the one lever
// never combined with the modern body (counted vmcnt, raw barriers,
// conflict-free swizzle, fp16 logits). Everything else = r17.
// B=2,S=1024,D=1024,L=8,V=32000. fp32 in/out.
// ---------------------------------------------------------------------------

using short8 = __attribute__((ext_vector_type(8))) short;
using half8  = __attribute__((ext_vector_type(8))) _Float16;
using half4  = __attribute__((ext_vector_type(4))) _Float16;
using f32x4  = __attribute__((ext_vector_type(4))) float;

#define DEVI __device__ __forceinline__

DEVI float sigm(float x) { return 1.0f / (1.0f + expf(-x)); }

DEVI float block_sum256(float v) {
  #pragma unroll
  for (int o = 32; o > 0; o >>= 1) v += __shfl_down(v, o, 64);
  __shared__ float sm[4];
  if ((threadIdx.x & 63) == 0) sm[threadIdx.x >> 6] = v;
  __syncthreads();
  float t = sm[0] + sm[1] + sm[2] + sm[3];
  __syncthreads();
  return t;
}

DEVI void gload16(const void* g, void* l) {    // async global->LDS, 16B/lane
  __builtin_amdgcn_global_load_lds(
      (const __attribute__((address_space(1))) unsigned*)g,
      (__attribute__((address_space(3))) unsigned*)l, 16, 0, 0);
}

// ---------------------------------------------------------------------------
// gemm18h (HEAD): C[M,N]=A[M,K]*B[N,K]^T fp16. 128x128 tile, BK=32, 4 waves
// (2x2, wave 64x64). 32KB LDS dbuf -> ~4 blocks/CU. Per K-tile:
//   vmcnt(4|0) -> barrier -> 8 ds_reads -> lgkmcnt(0) -> barrier ->
//   stage(t+2) -> sched_barrier -> 16 MFMA (setprio).
// Swizzle: 16B slot ^= ((row>>1)&3) on source AND read. fp16 logits out +
// fused per-row sum/sumsq partials (fp32 accumulators).
// ---------------------------------------------------------------------------
__global__ __launch_bounds__(256, 4) void gemm18h(
    const _Float16* __restrict__ A, const _Float16* __restrict__ B,
    int M, int N, int K,
    _Float16* __restrict__ outL16, float* __restrict__ psum,
    float* __restrict__ psq)
{
  __shared__ __align__(16) unsigned short lds[2][2][128 * 32];   // 32 KB
  const int tid  = threadIdx.x;
  const int lane = tid & 63, wid = tid >> 6;    // 4 waves
  const int wr = wid >> 1, wc = wid & 1;        // 2 x 2 wave grid
  const int myr = lane & 15;
  const int kq  = lane >> 4;                    // 8-elem k-slot 0..3

  const int nwg  = gridDim.x;
  const int flat = blockIdx.x;
  const int swz  = (flat & 7) * (nwg >> 3) + (flat >> 3);
  const int MT   = M >> 7;                      // 16
  const int m0   = (swz % MT) * 128;
  const int nt   = swz / MT;
  const int n0   = nt * 128;
  const int NT   = K / 32;                      // 32

  // stage one K-tile: per array 128 rows x 32 cols x 2B = 8KB = 2 gloads/thr
  auto stage = [&](int b, int k0) {
    #pragma unroll
    for (int q = 0; q < 2; ++q) {
      const int row  = q * 64 + wid * 16 + (lane >> 2);
      const int scol = ((lane & 3) ^ ((row >> 1) & 3)) << 3;  // pre-swizzled
      const int lb   = (q * 64 + wid * 16) * 32;              // wave-uniform
      gload16(A + (size_t)(m0 + row) * K + k0 + scol, &lds[b][0][lb]);
      gload16(B + (size_t)(n0 + row) * K + k0 + scol, &lds[b][1][lb]);
    }
  };

  f32x4 acc[4][4] = {};

  stage(0, 0);
  stage(1, 32);
  for (int t = 0; t < NT; ++t) {
    const int b = t & 1;
    if (t + 1 < NT) { asm volatile("s_waitcnt vmcnt(4)" ::: "memory"); }
    else            { asm volatile("s_waitcnt vmcnt(0)" ::: "memory"); }
    __builtin_amdgcn_s_barrier();               // tile t visible everywhere
    asm volatile("" ::: "memory");

    short8 af[4], bf[4];
    #pragma unroll
    for (int i = 0; i < 4; ++i) {
      const int ra = wr * 64 + i * 16 + myr;
      af[i] = *(const short8*)&lds[b][0][ra * 32 + ((kq ^ ((ra >> 1) & 3)) << 3)];
    }
    #pragma unroll
    for (int j = 0; j < 4; ++j) {
      const int rb = wc * 64 + j * 16 + myr;
      bf[j] = *(const short8*)&lds[b][1][rb * 32 + ((kq ^ ((rb >> 1) & 3)) << 3)];
    }
    asm volatile("s_waitcnt lgkmcnt(0)" ::: "memory");
    __builtin_amdgcn_s_barrier();               // all waves done reading buf b
    asm volatile("" ::: "memory");
    if (t + 2 < NT) stage(b, (t + 2) * 32);     // gloads fly under the MFMAs
    __builtin_amdgcn_sched_barrier(0);
    __builtin_amdgcn_s_setprio(1);
    #pragma unroll
    for (int i = 0; i < 4; ++i)
      #pragma unroll
      for (int j = 0; j < 4; ++j)
        acc[i][j] = __builtin_amdgcn_mfma_f32_16x16x32_f16(
            __builtin_bit_cast(half8, af[i]), __builtin_bit_cast(half8, bf[j]),
            acc[i][j], 0, 0, 0);
    __builtin_amdgcn_s_setprio(0);
  }

  // epilogue: C/D frag row=(lane>>4)*4+r, col=lane&15 — fp16 logits
  #pragma unroll
  for (int i = 0; i < 4; ++i) {
    const int rbase = m0 + wr * 64 + i * 16 + (kq << 2);
    #pragma unroll
    for (int j = 0; j < 4; ++j) {
      const int col = n0 + wc * 64 + j * 16 + myr;
      #pragma unroll
      for (int r = 0; r < 4; ++r)
        outL16[(size_t)(rbase + r) * N + col] = (_Float16)acc[i][j][r];
    }
  }

  // fused per-row stats over this wave's 64 output cols (validated r9)
  const int PW = N >> 6;
  const int pcol = (n0 >> 6) + wc;
  #pragma unroll
  for (int i = 0; i < 4; ++i)
    #pragma unroll
    for (int r = 0; r < 4; ++r) {
      float s = 0.f, ss = 0.f;
      #pragma unroll
      for (int j = 0; j < 4; ++j) {
        float v = acc[i][j][r];
        s += v; ss += v * v;
      }
      #pragma unroll
      for (int mk = 1; mk < 16; mk <<= 1) {
        s  += __shfl_xor(s,  mk, 64);
        ss += __shfl_xor(ss, mk, 64);
      }
      if (myr == i * 4 + r) {
        const int row = m0 + wr * 64 + i * 16 + kq * 4 + r;
        psum[(size_t)row * PW + pcol] = s;
        psq [(size_t)row * PW + pcol] = ss;
      }
    }
}

// ---------------------------------------------------------------------------
// gemm16 (layers, unchanged from r16/r17): 128x128 tile, 8 waves (2x4, wave
// tile 64x32), BK=64, 64KB LDS dbuf, counted vmcnt(4), slot^=(row&7) swizzle.
// EPI: 1 keygen->vaT16 chan-major +act; 2 +bias,silu,fp16; 4 x+=C; 5 fp16 part.
// ---------------------------------------------------------------------------
template<int EPI, int KSPLIT>
__global__ __launch_bounds__(512, 2) void gemm16(
    const _Float16* __restrict__ A, const _Float16* __restrict__ B,
    int M, int N, int K,
    float* __restrict__ outF, _Float16* __restrict__ outH,
    const float* __restrict__ bias, int halfN)
{
  __shared__ __align__(16) unsigned short lds[2][2][128 * 64];   // 64 KB
  const int tid  = threadIdx.x;
  const int lane = tid & 63, wid = tid >> 6;     // 8 waves
  const int wr = wid >> 2, wc = wid & 3;         // 2 x 4 wave grid
  const int myr = lane & 15;
  const int kq  = lane >> 4;

  const int nwg  = gridDim.x;
  const int flat = blockIdx.x;
  const int swz  = (flat & 7) * (nwg >> 3) + (flat >> 3);
  const int ks   = (KSPLIT > 1) ? (swz % KSPLIT) : 0;
  const int tile = (KSPLIT > 1) ? (swz / KSPLIT) : swz;
  const int MT   = M >> 7;
  const int m0   = (tile % MT) * 128;
  const int n0   = (tile / MT) * 128;
  const int Kc   = K / KSPLIT;
  const int kbase = ks * Kc;
  const int NT   = Kc / 64;

  auto stage = [&](int b, int k0) {
    #pragma unroll
    for (int q = 0; q < 2; ++q) {
      const int row  = q * 64 + wid * 8 + (lane >> 3);
      const int scol = ((lane & 7) ^ (row & 7)) << 3;
      const int lb   = (q * 64 + wid * 8) * 64;        // wave-uniform ushort
      gload16(A + (size_t)(m0 + row) * K + k0 + scol, &lds[b][0][lb]);
      gload16(B + (size_t)(n0 + row) * K + k0 + scol, &lds[b][1][lb]);
    }
  };

  f32x4 acc[4][2] = {};

  stage(0, kbase);
  stage(1, kbase + 64);
  for (int t = 0; t < NT; ++t) {
    const int b = t & 1;
    if (t + 1 < NT) { asm volatile("s_waitcnt vmcnt(4)" ::: "memory"); }
    else            { asm volatile("s_waitcnt vmcnt(0)" ::: "memory"); }
    __builtin_amdgcn_s_barrier();
    asm volatile("" ::: "memory");

    #pragma unroll
    for (int kk = 0; kk < 2; ++kk) {
      short8 af[4], bf[2];
      #pragma unroll
      for (int i = 0; i < 4; ++i) {
        const int ra = wr * 64 + i * 16 + myr;
        af[i] = *(const short8*)&lds[b][0][ra * 64 + (((kk * 4 + kq) ^ (ra & 7)) << 3)];
      }
      #pragma unroll
      for (int j = 0; j < 2; ++j) {
        const int rb = wc * 32 + j * 16 + myr;
        bf[j] = *(const short8*)&lds[b][1][rb * 64 + (((kk * 4 + kq) ^ (rb & 7)) << 3)];
      }
      __builtin_amdgcn_s_setprio(1);
      #pragma unroll
      for (int i = 0; i < 4; ++i)
        #pragma unroll
        for (int j = 0; j < 2; ++j)
          acc[i][j] = __builtin_amdgcn_mfma_f32_16x16x32_f16(
              __builtin_bit_cast(half8, af[i]), __builtin_bit_cast(half8, bf[j]),
              acc[i][j], 0, 0, 0);
      __builtin_amdgcn_s_setprio(0);
    }

    asm volatile("s_waitcnt lgkmcnt(0)" ::: "memory");
    __builtin_amdgcn_s_barrier();
    asm volatile("" ::: "memory");
    if (t + 2 < NT) stage(b, kbase + (t + 2) * 64);
  }

  // epilogue: C/D frag row=(lane>>4)*4+r, col=lane&15 (m89)
  const size_t MN = (size_t)M * N;
  #pragma unroll
  for (int i = 0; i < 4; ++i) {
    const int rbase = m0 + wr * 64 + i * 16 + (kq << 2);
    #pragma unroll
    for (int j = 0; j < 2; ++j) {
      const int col = n0 + wc * 32 + j * 16 + myr;
      if constexpr (EPI == 1) {                    // channel-major vaT16[col][row]
        half4 hv;
        #pragma unroll
        for (int r = 0; r < 4; ++r) {
          float c = acc[i][j][r];
          hv[r] = (_Float16)((col < halfN) ? (tanhf(c) * 3.14159265358979323846f)
                                           : sigm(c));
        }
        *(half4*)&outH[(size_t)col * M + rbase] = hv;
      } else {
        #pragma unroll
        for (int r = 0; r < 4; ++r) {
          float c = acc[i][j][r];
          const size_t idx = (size_t)(rbase + r) * N + col;
          if constexpr (EPI == 2) {
            c += bias[col];
            outH[idx] = (_Float16)(c * sigm(c));   // silu
          } else if constexpr (EPI == 4) {
            float xn = outF[idx] + c;              // x += delta@plastic
            outF[idx] = xn;
            outH[idx] = (_Float16)xn;
          } else if constexpr (EPI == 5) {
            outH[(size_t)ks * MN + idx] = (_Float16)c;  // fp16 partial
          }
        }
      }
    }
  }
}

// ---------------------------------------------------------------------------
// Fused lerp-scan + causal dwconv3, fp16 vaT input (unchanged).
// ---------------------------------------------------------------------------
__global__ __launch_bounds__(256) void scanconv(
    const _Float16* __restrict__ vaT, const float* __restrict__ cw,
    const float* __restrict__ cb, _Float16* __restrict__ z16,
    int S, int D, int M)
{
  const int dl = threadIdx.x & 7;
  const int c  = threadIdx.x >> 3;
  const int ch = blockIdx.x * 8 + dl;
  const int b = ch >> 10, d = ch & 1023;
  const _Float16* vrow = vaT + (size_t)d * M + b * S;
  const _Float16* arow = vaT + (size_t)(D + d) * M + b * S;
  const int s0 = c * 32;

  f32x4 vr[8], ar[8];
  float A = 1.f, Bv = 0.f, Apm = 1.f, Bpm = 0.f;
  #pragma unroll
  for (int t = 0; t < 8; ++t) {
    half4 v4 = *(const half4*)&vrow[s0 + t * 4];
    half4 a4 = *(const half4*)&arow[s0 + t * 4];
    #pragma unroll
    for (int r = 0; r < 4; ++r) {
      vr[t][r] = (float)v4[r];
      ar[t][r] = (float)a4[r];
      if (t * 4 + r == 31) { Apm = A; Bpm = Bv; }
      float na = 1.f - ar[t][r];
      A *= na;
      Bv = Bv * na + ar[t][r] * vr[t][r];
    }
  }
  __shared__ float Asm[32][9], Bsm[32][9], Aps[32][9], Bps[32][9];
  Asm[c][dl] = A; Bsm[c][dl] = Bv; Aps[c][dl] = Apm; Bps[c][dl] = Bpm;
  __syncthreads();
  if (threadIdx.x < 8) {
    float run = 0.f;
    for (int cc = 0; cc < 32; ++cc) {
      float A_ = Asm[cc][dl], B_ = Bsm[cc][dl];
      Bsm[cc][dl] = run;
      run = A_ * run + B_;
    }
  }
  __syncthreads();
  float hm1 = Bsm[c][dl];
  float hm2 = (c == 0) ? 0.f
            : (Aps[c - 1][dl] * Bsm[c - 1][dl] + Bps[c - 1][dl]);

  const float w0 = cw[d * 3 + 0], w1 = cw[d * 3 + 1], w2 = cw[d * 3 + 2];
  const float bc = cb[d];
  #pragma unroll
  for (int t = 0; t < 8; ++t) {
    #pragma unroll
    for (int r = 0; r < 4; ++r) {
      float h = hm1 + ar[t][r] * (vr[t][r] - hm1);
      float z = h + bc + w0 * hm2 + w1 * hm1 + w2 * h;
      z16[(size_t)(b * S + s0 + t * 4 + r) * D + d] = (_Float16)z;
      hm2 = hm1; hm1 = h;
    }
  }
}

// v = p0+p1+bias (fp16 partials); delta = rmsnorm(v)*nw; x += delta
__global__ __launch_bounds__(256) void rms_fuse(
    const _Float16* __restrict__ p, const float* __restrict__ bias,
    const float* __restrict__ nw, float* __restrict__ x,
    _Float16* __restrict__ o16, int D, int mode, size_t MN)
{
  const size_t base = (size_t)blockIdx.x * D;
  float vloc[4]; float ss = 0.f;
  #pragma unroll
  for (int q = 0; q < 4; ++q) {
    int d = threadIdx.x + q * 256;
    float v = (float)p[base + d] + (float)p[MN + base + d] + bias[d];
    vloc[q] = v; ss += v * v;
  }
  ss = block_sum256(ss);
  float r = 1.f / sqrtf(ss / D + 1e-8f);
  #pragma unroll
  for (int q = 0; q < 4; ++q) {
    int d = threadIdx.x + q * 256;
    float delta = vloc[q] * r * nw[d];
    float xn = x[base + d] + delta;
    x[base + d] = xn;
    o16[base + d] = (_Float16)(mode ? delta : xn);
  }
}

__global__ __launch_bounds__(256) void embed_norm(
    const int* __restrict__ ids, const float* __restrict__ emb,
    const float* __restrict__ pos,
    float* __restrict__ x, _Float16* __restrict__ x16, int S, int D)
{
  const int rowi = blockIdx.x;
  const int s = rowi % S;
  const int tok = ids[rowi];
  const size_t eb = (size_t)tok * D, pb = (size_t)s * D, xb = (size_t)rowi * D;
  float vloc[4]; float ss = 0.f;
  #pragma unroll
  for (int q = 0; q < 4; ++q) {
    int d = threadIdx.x + q * 256;
    float v = emb[eb + d] + pos[pb + d];
    vloc[q] = v; ss += v * v;
  }
  ss = block_sum256(ss);
  float r = 1.f / fmaxf(sqrtf(ss), 1e-12f);
  #pragma unroll
  for (int q = 0; q < 4; ++q) {
    int d = threadIdx.x + q * 256;
    float v = vloc[q] * r;
    x[xb + d] = v;
    x16[xb + d] = (_Float16)v;
  }
}

__global__ __launch_bounds__(256) void final_norm(
    const float* __restrict__ x, const float* __restrict__ w,
    _Float16* __restrict__ xf, int D)
{
  const size_t base = (size_t)blockIdx.x * D;
  float s1 = 0.f, s2 = 0.f;
  float vloc[4], wloc[4];
  #pragma unroll
  for (int q = 0; q < 4; ++q) {
    int d = threadIdx.x + q * 256;
    float v = x[base + d], ww = w[d];
    vloc[q] = v; wloc[q] = ww;
    s1 += v * v; s2 += v * ww * v * ww;
  }
  s1 = block_sum256(s1);
  s2 = block_sum256(s2);
  float r1 = 1.f / sqrtf(s1 / D + 1e-8f);
  float m2 = r1 * r1 * (s2 / D);
  float r2 = 1.f / sqrtf(m2 + 1e-8f);
  float sc = r1 * r2 * 0.8f;
  #pragma unroll
  for (int q = 0; q < 4; ++q) {
    int d = threadIdx.x + q * 256;
    xf[base + d] = (_Float16)(vloc[q] * wloc[q] * sc);
  }
}

// reduce partials -> scale; read fp16 logits, scale+clip -> fp32 out
__global__ __launch_bounds__(256) void fix_row(
    const _Float16* __restrict__ lg, float* __restrict__ out,
    const float* __restrict__ psum, const float* __restrict__ psq,
    int PW, int V)
{
  const int row = blockIdx.x;
  float s = 0.f, q = 0.f;
  for (int j = threadIdx.x; j < PW; j += 256) {
    s += psum[(size_t)row * PW + j];
    q += psq [(size_t)row * PW + j];
  }
  s = block_sum256(s);
  q = block_sum256(q);
  float mean = s / V;
  float var = (q - (float)V * mean * mean) / (float)(V - 1);
  var = fmaxf(var, 0.f);
  const float sc = 1.f / fmaxf(sqrtf(var), 1.f);
  const _Float16* rp16 = lg + (size_t)row * V;
  float* rowp = out + (size_t)row * V;
  for (int j = threadIdx.x * 8; j < V; j += 2048) {
    half8 h = *(const half8*)&rp16[j];
    f32x4 lo, hi;
    #pragma unroll
    for (int t = 0; t < 4; ++t) {
      lo[t] = fminf(fmaxf((float)h[t]     * sc, -10.f), 10.f);
      hi[t] = fminf(fmaxf((float)h[t + 4] * sc, -10.f), 10.f);
    }
    *(f32x4*)&rowp[j]     = lo;
    *(f32x4*)&rowp[j + 4] = hi;
  }
}

__global__ void tsplit16(const float* __restrict__ W, _Float16* __restrict__ WT,
                         int K, int N)
{
  __shared__ float t[32][33];
  const size_t bo = (size_t)blockIdx.z * K * N;
  const int tx = threadIdx.x, ty = threadIdx.y;
  #pragma unroll
  for (int i = 0; i < 32; i += 8) {
    int kk = blockIdx.y * 32 + ty + i;
    int nn = blockIdx.x * 32 + tx;
    t[ty + i][tx] = W[bo + (size_t)kk * N + nn];
  }
  __syncthreads();
  #pragma unroll
  for (int i = 0; i < 32; i += 8) {
    int nn = blockIdx.x * 32 + ty + i;
    int kk = blockIdx.y * 32 + tx;
    WT[bo + (size_t)nn * K + kk] = (_Float16)t[tx][ty + i];
  }
}

__global__ void cvt_f16(const float* __restrict__ in, _Float16* __restrict__ o, size_t n)
{
  for (size_t i = (size_t)blockIdx.x * 256 + threadIdx.x; i < n;
       i += (size_t)gridDim.x * 256)
    o[i] = (_Float16)in[i];
}

// ---------------------------------------------------------------------------
extern "C" void kernel_launch(void* const* d_in, const int* in_sizes, int n_in,
                              void* d_out, int out_size, void* d_ws, size_t ws_size,
                              hipStream_t stream)
{
  (void)in_sizes; (void)n_in; (void)out_size; (void)ws_size;
  const int*   ids = (const int*)  d_in[0];
  const float* emb = (const float*)d_in[1];
  const float* pos = (const float*)d_in[2];
  const float* kw  = (const float*)d_in[3];
  const float* cw  = (const float*)d_in[4];
  const float* cb  = (const float*)d_in[5];
  const float* w1  = (const float*)d_in[6];
  const float* b1  = (const float*)d_in[7];
  const float* w2  = (const float*)d_in[8];
  const float* b2  = (const float*)d_in[9];
  const float* nw  = (const float*)d_in[10];
  const float* pl  = (const float*)d_in[11];
  const float* fnw = (const float*)d_in[12];
  float* out = (float*)d_out;

  constexpr int B = 2, S = 1024, D = 1024, L = 8, V = 32000;
  constexpr int M = B * S;
  const size_t MN = (size_t)M * D;

  size_t off = 0;
  auto alloc = [&](size_t bytes) {
    char* p = (char*)d_ws + off;
    off += (bytes + 255) & ~(size_t)255;
    return (void*)p;
  };
  _Float16* kwT  = (_Float16*)alloc((size_t)L * 2 * D * D * 2);
  _Float16* w1T  = (_Float16*)alloc((size_t)L * 2 * D * D * 2);
  _Float16* w2T  = (_Float16*)alloc((size_t)L * 2 * D * D * 2);
  _Float16* plT  = (_Float16*)alloc((size_t)4 * D * D * 2);
  _Float16* emb16 = (_Float16*)alloc((size_t)V * D * 2);
  float* x    = (float*)alloc(MN * 4);
  _Float16* x16 = (_Float16*)alloc(MN * 2);
  _Float16* vaT16 = (_Float16*)alloc((size_t)M * 2 * D * 2);  // [2D][M] fp16
  _Float16* p16   = (_Float16*)alloc(2 * MN * 2);             // fp16 partials
  _Float16* z16 = (_Float16*)alloc(MN * 2);
  _Float16* u16 = (_Float16*)alloc((size_t)M * 2 * D * 2);
  _Float16* d16 = (_Float16*)alloc(MN * 2);
  _Float16* xf16 = (_Float16*)alloc(MN * 2);
  _Float16* lg16 = (_Float16*)alloc((size_t)M * V * 2);       // fp16 logits
  float* psum = (float*)alloc((size_t)M * (V >> 6) * 4);
  float* psq  = (float*)alloc((size_t)M * (V >> 6) * 4);

  const int PW = V >> 6;                 // 500

  {
    dim3 tb(32, 8);
    tsplit16<<<dim3(2 * D / 32, D / 32, L), tb, 0, stream>>>(kw, kwT, D, 2 * D);
    tsplit16<<<dim3(2 * D / 32, D / 32, L), tb, 0, stream>>>(w1, w1T, D, 2 * D);
    tsplit16<<<dim3(D / 32, 2 * D / 32, L), tb, 0, stream>>>(w2, w2T, 2 * D, D);
    tsplit16<<<dim3(D / 32, D / 32, 4),     tb, 0, stream>>>(pl, plT, D, D);
    cvt_f16<<<4096, 256, 0, stream>>>(emb, emb16, (size_t)V * D);
  }

  embed_norm<<<M, 256, 0, stream>>>(ids, emb, pos, x, x16, S, D);

  for (int i = 0; i < L; ++i) {
    const _Float16* kwi = kwT + (size_t)i * 2 * D * D;
    const _Float16* w1i = w1T + (size_t)i * 2 * D * D;
    const _Float16* w2i = w2T + (size_t)i * 2 * D * D;

    // G1: vaT16 = act(x@kw), channel-major fp16, fused tanh/sigm
    gemm16<1, 1><<<(M / 128) * (2 * D / 128), 512, 0, stream>>>(
        x16, kwi, M, 2 * D, D, nullptr, vaT16, nullptr, D);

    scanconv<<<B * D / 8, 256, 0, stream>>>(
        vaT16, cw + (size_t)i * D * 3, cb + (size_t)i * D, z16, S, D, M);

    // G2: u = silu(z@w1 + b1) -> fp16
    gemm16<2, 1><<<(M / 128) * (2 * D / 128), 512, 0, stream>>>(
        z16, w1i, M, 2 * D, D, nullptr, u16, b1 + (size_t)i * 2 * D, 0);

    // G3: hf partials (fp16) = u@w2 (split-K x2)
    gemm16<5, 2><<<(M / 128) * (D / 128) * 2, 512, 0, stream>>>(
        u16, w2i, M, D, 2 * D, nullptr, p16, nullptr, 0);

    const int mode = (i >= L - 4) ? 1 : 0;
    rms_fuse<<<M, 256, 0, stream>>>(p16, b2 + (size_t)i * D, nw + (size_t)i * D,
                                    x, mode ? d16 : x16, D, mode, MN);
    if (mode) {
      const _Float16* pli = plT + (size_t)(i - 4) * D * D;
      // G4: x += delta@plastic (direct accumulate, writes x16)
      gemm16<4, 1><<<(M / 128) * (D / 128), 512, 0, stream>>>(
          d16, pli, M, D, D, x, x16, nullptr, 0);
    }
  }

  final_norm<<<M, 256, 0, stream>>>(x, fnw, xf16, D);

  // LM head: 128^2 high-occupancy schedule, fp16 logits + fused row stats
  gemm18h<<<(M / 128) * (V / 128), 256, 0, stream>>>(
      xf16, emb16, M, V, D, lg16, psum, psq);

  // scale+clip: fp16 logits -> fp32 d_out
  fix_row<<<M, 256, 0, stream>>>(lg16, out, psum, psq, PW, V);
}

// Round 19
// 1014.333 us; speedup vs baseline: 1.0169x; 1.0169x over previous
//
#include <hip/hip_runtime.h>

// ---------------------------------------------------------------------------
// MRT12 v19 (= r17, measured best 1016us): head gemm17h 256^2 BK=32 fp16
// logits + fused row stats; layers gemm16 8-wave BK=64, fp16 partials/vaT;
// fused scan+conv; fix_row reads fp16 logits -> fp32 out.
// B=2,S=1024,D=1024,L=8,V=32000. fp32 in/out.
// ---------------------------------------------------------------------------

using short8 = __attribute__((ext_vector_type(8))) short;
using half8  = __attribute__((ext_vector_type(8))) _Float16;
using half4  = __attribute__((ext_vector_type(4))) _Float16;
using f32x4  = __attribute__((ext_vector_type(4))) float;

#define DEVI __device__ __forceinline__

DEVI float sigm(float x) { return 1.0f / (1.0f + expf(-x)); }

DEVI float block_sum256(float v) {
  #pragma unroll
  for (int o = 32; o > 0; o >>= 1) v += __shfl_down(v, o, 64);
  __shared__ float sm[4];
  if ((threadIdx.x & 63) == 0) sm[threadIdx.x >> 6] = v;
  __syncthreads();
  float t = sm[0] + sm[1] + sm[2] + sm[3];
  __syncthreads();
  return t;
}

DEVI void gload16(const void* g, void* l) {    // async global->LDS, 16B/lane
  __builtin_amdgcn_global_load_lds(
      (const __attribute__((address_space(1))) unsigned*)g,
      (__attribute__((address_space(3))) unsigned*)l, 16, 0, 0);
}

// ---------------------------------------------------------------------------
// gemm17h (HEAD): 256x256, BK=32, 8 waves, 64KB LDS, counted vmcnt(4).
// fp16 logits out + fused per-row sum/sumsq partials (fp32 accumulators).
// ---------------------------------------------------------------------------
__global__ __launch_bounds__(512, 2) void gemm17h(
    const _Float16* __restrict__ A, const _Float16* __restrict__ B,
    int M, int N, int K,
    _Float16* __restrict__ outL16, float* __restrict__ psum,
    float* __restrict__ psq)
{
  __shared__ __align__(16) unsigned short lds[2][2][256 * 32];   // 64 KB
  const int tid  = threadIdx.x;
  const int lane = tid & 63, wid = tid >> 6;
  const int wr = wid >> 2, wc = wid & 3;        // 2 x 4 wave grid
  const int myr = lane & 15;
  const int kq  = lane >> 4;                    // 8-elem k-slot 0..3

  const int nwg  = gridDim.x;
  const int flat = blockIdx.x;
  const int swz  = (flat & 7) * (nwg >> 3) + (flat >> 3);
  const int MT   = M >> 8;
  const int m0   = (swz % MT) * 256;
  const int nt   = swz / MT;
  const int n0   = nt * 256;
  const int NT   = K / 32;                      // 32

  auto stage = [&](int b, int k0) {
    #pragma unroll
    for (int q = 0; q < 2; ++q) {
      const int row  = q * 128 + wid * 16 + (lane >> 2);
      const int scol = ((lane & 3) ^ ((row >> 1) & 3)) << 3;  // pre-swizzled
      const int lb   = (q * 128 + wid * 16) * 32;             // wave-uniform
      gload16(A + (size_t)(m0 + row) * K + k0 + scol, &lds[b][0][lb]);
      gload16(B + (size_t)(n0 + row) * K + k0 + scol, &lds[b][1][lb]);
    }
  };

  f32x4 acc[8][4] = {};

  stage(0, 0);
  stage(1, 32);
  for (int t = 0; t < NT; ++t) {
    const int b = t & 1;
    if (t + 1 < NT) { asm volatile("s_waitcnt vmcnt(4)" ::: "memory"); }
    else            { asm volatile("s_waitcnt vmcnt(0)" ::: "memory"); }
    __builtin_amdgcn_s_barrier();               // tile t visible everywhere
    asm volatile("" ::: "memory");

    short8 af[8], bf[4];
    #pragma unroll
    for (int i = 0; i < 8; ++i) {
      const int ra = wr * 128 + i * 16 + myr;
      af[i] = *(const short8*)&lds[b][0][ra * 32 + ((kq ^ ((ra >> 1) & 3)) << 3)];
    }
    #pragma unroll
    for (int j = 0; j < 4; ++j) {
      const int rb = wc * 64 + j * 16 + myr;
      bf[j] = *(const short8*)&lds[b][1][rb * 32 + ((kq ^ ((rb >> 1) & 3)) << 3)];
    }
    asm volatile("s_waitcnt lgkmcnt(0)" ::: "memory");
    __builtin_amdgcn_s_barrier();               // all waves done reading buf b
    asm volatile("" ::: "memory");
    if (t + 2 < NT) stage(b, (t + 2) * 32);     // gloads fly under the MFMAs
    __builtin_amdgcn_sched_barrier(0);
    __builtin_amdgcn_s_setprio(1);
    #pragma unroll
    for (int i = 0; i < 8; ++i)
      #pragma unroll
      for (int j = 0; j < 4; ++j)
        acc[i][j] = __builtin_amdgcn_mfma_f32_16x16x32_f16(
            __builtin_bit_cast(half8, af[i]), __builtin_bit_cast(half8, bf[j]),
            acc[i][j], 0, 0, 0);
    __builtin_amdgcn_s_setprio(0);
  }

  // epilogue: C/D frag row=(lane>>4)*4+r, col=lane&15 — fp16 logits
  #pragma unroll
  for (int i8 = 0; i8 < 8; ++i8) {
    const int rbase = m0 + wr * 128 + i8 * 16 + (kq << 2);
    #pragma unroll
    for (int j4 = 0; j4 < 4; ++j4) {
      const int col = n0 + wc * 64 + j4 * 16 + myr;
      #pragma unroll
      for (int r = 0; r < 4; ++r)
        outL16[(size_t)(rbase + r) * N + col] = (_Float16)acc[i8][j4][r];
    }
  }

  // fused per-row stats from fp32 accumulators
  const int PW = N >> 6;
  const int pcol = (n0 >> 6) + wc;
  #pragma unroll
  for (int i8 = 0; i8 < 8; ++i8)
    #pragma unroll
    for (int r = 0; r < 4; ++r) {
      float s = 0.f, ss = 0.f;
      #pragma unroll
      for (int j4 = 0; j4 < 4; ++j4) {
        float v = acc[i8][j4][r];
        s += v; ss += v * v;
      }
      #pragma unroll
      for (int mk = 1; mk < 16; mk <<= 1) {
        s  += __shfl_xor(s,  mk, 64);
        ss += __shfl_xor(ss, mk, 64);
      }
      if (myr == ((i8 * 4 + r) & 15)) {
        const int row = m0 + wr * 128 + i8 * 16 + kq * 4 + r;
        psum[(size_t)row * PW + pcol] = s;
        psq [(size_t)row * PW + pcol] = ss;
      }
    }
}

// ---------------------------------------------------------------------------
// gemm16 (layers): 128x128 tile, 8 waves (2x4, wave tile 64x32), BK=64,
// 64KB LDS dbuf, counted vmcnt(4), slot^=(row&7) swizzle.
// EPI: 1 keygen->vaT16 chan-major +act; 2 +bias,silu,fp16; 4 x+=C; 5 fp16 part.
// ---------------------------------------------------------------------------
template<int EPI, int KSPLIT>
__global__ __launch_bounds__(512, 2) void gemm16(
    const _Float16* __restrict__ A, const _Float16* __restrict__ B,
    int M, int N, int K,
    float* __restrict__ outF, _Float16* __restrict__ outH,
    const float* __restrict__ bias, int halfN)
{
  __shared__ __align__(16) unsigned short lds[2][2][128 * 64];   // 64 KB
  const int tid  = threadIdx.x;
  const int lane = tid & 63, wid = tid >> 6;     // 8 waves
  const int wr = wid >> 2, wc = wid & 3;         // 2 x 4 wave grid
  const int myr = lane & 15;
  const int kq  = lane >> 4;

  const int nwg  = gridDim.x;
  const int flat = blockIdx.x;
  const int swz  = (flat & 7) * (nwg >> 3) + (flat >> 3);
  const int ks   = (KSPLIT > 1) ? (swz % KSPLIT) : 0;
  const int tile = (KSPLIT > 1) ? (swz / KSPLIT) : swz;
  const int MT   = M >> 7;
  const int m0   = (tile % MT) * 128;
  const int n0   = (tile / MT) * 128;
  const int Kc   = K / KSPLIT;
  const int kbase = ks * Kc;
  const int NT   = Kc / 64;

  auto stage = [&](int b, int k0) {
    #pragma unroll
    for (int q = 0; q < 2; ++q) {
      const int row  = q * 64 + wid * 8 + (lane >> 3);
      const int scol = ((lane & 7) ^ (row & 7)) << 3;
      const int lb   = (q * 64 + wid * 8) * 64;        // wave-uniform ushort
      gload16(A + (size_t)(m0 + row) * K + k0 + scol, &lds[b][0][lb]);
      gload16(B + (size_t)(n0 + row) * K + k0 + scol, &lds[b][1][lb]);
    }
  };

  f32x4 acc[4][2] = {};

  stage(0, kbase);
  stage(1, kbase + 64);
  for (int t = 0; t < NT; ++t) {
    const int b = t & 1;
    if (t + 1 < NT) { asm volatile("s_waitcnt vmcnt(4)" ::: "memory"); }
    else            { asm volatile("s_waitcnt vmcnt(0)" ::: "memory"); }
    __builtin_amdgcn_s_barrier();
    asm volatile("" ::: "memory");

    #pragma unroll
    for (int kk = 0; kk < 2; ++kk) {
      short8 af[4], bf[2];
      #pragma unroll
      for (int i = 0; i < 4; ++i) {
        const int ra = wr * 64 + i * 16 + myr;
        af[i] = *(const short8*)&lds[b][0][ra * 64 + (((kk * 4 + kq) ^ (ra & 7)) << 3)];
      }
      #pragma unroll
      for (int j = 0; j < 2; ++j) {
        const int rb = wc * 32 + j * 16 + myr;
        bf[j] = *(const short8*)&lds[b][1][rb * 64 + (((kk * 4 + kq) ^ (rb & 7)) << 3)];
      }
      __builtin_amdgcn_s_setprio(1);
      #pragma unroll
      for (int i = 0; i < 4; ++i)
        #pragma unroll
        for (int j = 0; j < 2; ++j)
          acc[i][j] = __builtin_amdgcn_mfma_f32_16x16x32_f16(
              __builtin_bit_cast(half8, af[i]), __builtin_bit_cast(half8, bf[j]),
              acc[i][j], 0, 0, 0);
      __builtin_amdgcn_s_setprio(0);
    }

    asm volatile("s_waitcnt lgkmcnt(0)" ::: "memory");
    __builtin_amdgcn_s_barrier();
    asm volatile("" ::: "memory");
    if (t + 2 < NT) stage(b, kbase + (t + 2) * 64);
  }

  // epilogue: C/D frag row=(lane>>4)*4+r, col=lane&15 (m89)
  const size_t MN = (size_t)M * N;
  #pragma unroll
  for (int i = 0; i < 4; ++i) {
    const int rbase = m0 + wr * 64 + i * 16 + (kq << 2);
    #pragma unroll
    for (int j = 0; j < 2; ++j) {
      const int col = n0 + wc * 32 + j * 16 + myr;
      if constexpr (EPI == 1) {                    // channel-major vaT16[col][row]
        half4 hv;
        #pragma unroll
        for (int r = 0; r < 4; ++r) {
          float c = acc[i][j][r];
          hv[r] = (_Float16)((col < halfN) ? (tanhf(c) * 3.14159265358979323846f)
                                           : sigm(c));
        }
        *(half4*)&outH[(size_t)col * M + rbase] = hv;
      } else {
        #pragma unroll
        for (int r = 0; r < 4; ++r) {
          float c = acc[i][j][r];
          const size_t idx = (size_t)(rbase + r) * N + col;
          if constexpr (EPI == 2) {
            c += bias[col];
            outH[idx] = (_Float16)(c * sigm(c));   // silu
          } else if constexpr (EPI == 4) {
            float xn = outF[idx] + c;              // x += delta@plastic
            outF[idx] = xn;
            outH[idx] = (_Float16)xn;
          } else if constexpr (EPI == 5) {
            outH[(size_t)ks * MN + idx] = (_Float16)c;  // fp16 partial
          }
        }
      }
    }
  }
}

// ---------------------------------------------------------------------------
// Fused lerp-scan + causal dwconv3, fp16 vaT input.
// ---------------------------------------------------------------------------
__global__ __launch_bounds__(256) void scanconv(
    const _Float16* __restrict__ vaT, const float* __restrict__ cw,
    const float* __restrict__ cb, _Float16* __restrict__ z16,
    int S, int D, int M)
{
  const int dl = threadIdx.x & 7;
  const int c  = threadIdx.x >> 3;
  const int ch = blockIdx.x * 8 + dl;
  const int b = ch >> 10, d = ch & 1023;
  const _Float16* vrow = vaT + (size_t)d * M + b * S;
  const _Float16* arow = vaT + (size_t)(D + d) * M + b * S;
  const int s0 = c * 32;

  f32x4 vr[8], ar[8];
  float A = 1.f, Bv = 0.f, Apm = 1.f, Bpm = 0.f;
  #pragma unroll
  for (int t = 0; t < 8; ++t) {
    half4 v4 = *(const half4*)&vrow[s0 + t * 4];
    half4 a4 = *(const half4*)&arow[s0 + t * 4];
    #pragma unroll
    for (int r = 0; r < 4; ++r) {
      vr[t][r] = (float)v4[r];
      ar[t][r] = (float)a4[r];
      if (t * 4 + r == 31) { Apm = A; Bpm = Bv; }
      float na = 1.f - ar[t][r];
      A *= na;
      Bv = Bv * na + ar[t][r] * vr[t][r];
    }
  }
  __shared__ float Asm[32][9], Bsm[32][9], Aps[32][9], Bps[32][9];
  Asm[c][dl] = A; Bsm[c][dl] = Bv; Aps[c][dl] = Apm; Bps[c][dl] = Bpm;
  __syncthreads();
  if (threadIdx.x < 8) {
    float run = 0.f;
    for (int cc = 0; cc < 32; ++cc) {
      float A_ = Asm[cc][dl], B_ = Bsm[cc][dl];
      Bsm[cc][dl] = run;
      run = A_ * run + B_;
    }
  }
  __syncthreads();
  float hm1 = Bsm[c][dl];
  float hm2 = (c == 0) ? 0.f
            : (Aps[c - 1][dl] * Bsm[c - 1][dl] + Bps[c - 1][dl]);

  const float w0 = cw[d * 3 + 0], w1 = cw[d * 3 + 1], w2 = cw[d * 3 + 2];
  const float bc = cb[d];
  #pragma unroll
  for (int t = 0; t < 8; ++t) {
    #pragma unroll
    for (int r = 0; r < 4; ++r) {
      float h = hm1 + ar[t][r] * (vr[t][r] - hm1);
      float z = h + bc + w0 * hm2 + w1 * hm1 + w2 * h;
      z16[(size_t)(b * S + s0 + t * 4 + r) * D + d] = (_Float16)z;
      hm2 = hm1; hm1 = h;
    }
  }
}

// v = p0+p1+bias (fp16 partials); delta = rmsnorm(v)*nw; x += delta
__global__ __launch_bounds__(256) void rms_fuse(
    const _Float16* __restrict__ p, const float* __restrict__ bias,
    const float* __restrict__ nw, float* __restrict__ x,
    _Float16* __restrict__ o16, int D, int mode, size_t MN)
{
  const size_t base = (size_t)blockIdx.x * D;
  float vloc[4]; float ss = 0.f;
  #pragma unroll
  for (int q = 0; q < 4; ++q) {
    int d = threadIdx.x + q * 256;
    float v = (float)p[base + d] + (float)p[MN + base + d] + bias[d];
    vloc[q] = v; ss += v * v;
  }
  ss = block_sum256(ss);
  float r = 1.f / sqrtf(ss / D + 1e-8f);
  #pragma unroll
  for (int q = 0; q < 4; ++q) {
    int d = threadIdx.x + q * 256;
    float delta = vloc[q] * r * nw[d];
    float xn = x[base + d] + delta;
    x[base + d] = xn;
    o16[base + d] = (_Float16)(mode ? delta : xn);
  }
}

__global__ __launch_bounds__(256) void embed_norm(
    const int* __restrict__ ids, const float* __restrict__ emb,
    const float* __restrict__ pos,
    float* __restrict__ x, _Float16* __restrict__ x16, int S, int D)
{
  const int rowi = blockIdx.x;
  const int s = rowi % S;
  const int tok = ids[rowi];
  const size_t eb = (size_t)tok * D, pb = (size_t)s * D, xb = (size_t)rowi * D;
  float vloc[4]; float ss = 0.f;
  #pragma unroll
  for (int q = 0; q < 4; ++q) {
    int d = threadIdx.x + q * 256;
    float v = emb[eb + d] + pos[pb + d];
    vloc[q] = v; ss += v * v;
  }
  ss = block_sum256(ss);
  float r = 1.f / fmaxf(sqrtf(ss), 1e-12f);
  #pragma unroll
  for (int q = 0; q < 4; ++q) {
    int d = threadIdx.x + q * 256;
    float v = vloc[q] * r;
    x[xb + d] = v;
    x16[xb + d] = (_Float16)v;
  }
}

__global__ __launch_bounds__(256) void final_norm(
    const float* __restrict__ x, const float* __restrict__ w,
    _Float16* __restrict__ xf, int D)
{
  const size_t base = (size_t)blockIdx.x * D;
  float s1 = 0.f, s2 = 0.f;
  float vloc[4], wloc[4];
  #pragma unroll
  for (int q = 0; q < 4; ++q) {
    int d = threadIdx.x + q * 256;
    float v = x[base + d], ww = w[d];
    vloc[q] = v; wloc[q] = ww;
    s1 += v * v; s2 += v * ww * v * ww;
  }
  s1 = block_sum256(s1);
  s2 = block_sum256(s2);
  float r1 = 1.f / sqrtf(s1 / D + 1e-8f);
  float m2 = r1 * r1 * (s2 / D);
  float r2 = 1.f / sqrtf(m2 + 1e-8f);
  float sc = r1 * r2 * 0.8f;
  #pragma unroll
  for (int q = 0; q < 4; ++q) {
    int d = threadIdx.x + q * 256;
    xf[base + d] = (_Float16)(vloc[q] * wloc[q] * sc);
  }
}

// reduce partials -> scale; read fp16 logits, scale+clip -> fp32 out
__global__ __launch_bounds__(256) void fix_row(
    const _Float16* __restrict__ lg, float* __restrict__ out,
    const float* __restrict__ psum, const float* __restrict__ psq,
    int PW, int V)
{
  const int row = blockIdx.x;
  float s = 0.f, q = 0.f;
  for (int j = threadIdx.x; j < PW; j += 256) {
    s += psum[(size_t)row * PW + j];
    q += psq [(size_t)row * PW + j];
  }
  s = block_sum256(s);
  q = block_sum256(q);
  float mean = s / V;
  float var = (q - (float)V * mean * mean) / (float)(V - 1);
  var = fmaxf(var, 0.f);
  const float sc = 1.f / fmaxf(sqrtf(var), 1.f);
  const _Float16* rp16 = lg + (size_t)row * V;
  float* rowp = out + (size_t)row * V;
  for (int j = threadIdx.x * 8; j < V; j += 2048) {
    half8 h = *(const half8*)&rp16[j];
    f32x4 lo, hi;
    #pragma unroll
    for (int t = 0; t < 4; ++t) {
      lo[t] = fminf(fmaxf((float)h[t]     * sc, -10.f), 10.f);
      hi[t] = fminf(fmaxf((float)h[t + 4] * sc, -10.f), 10.f);
    }
    *(f32x4*)&rowp[j]     = lo;
    *(f32x4*)&rowp[j + 4] = hi;
  }
}

__global__ void tsplit16(const float* __restrict__ W, _Float16* __restrict__ WT,
                         int K, int N)
{
  __shared__ float t[32][33];
  const size_t bo = (size_t)blockIdx.z * K * N;
  const int tx = threadIdx.x, ty = threadIdx.y;
  #pragma unroll
  for (int i = 0; i < 32; i += 8) {
    int kk = blockIdx.y * 32 + ty + i;
    int nn = blockIdx.x * 32 + tx;
    t[ty + i][tx] = W[bo + (size_t)kk * N + nn];
  }
  __syncthreads();
  #pragma unroll
  for (int i = 0; i < 32; i += 8) {
    int nn = blockIdx.x * 32 + ty + i;
    int kk = blockIdx.y * 32 + tx;
    WT[bo + (size_t)nn * K + kk] = (_Float16)t[tx][ty + i];
  }
}

__global__ void cvt_f16(const float* __restrict__ in, _Float16* __restrict__ o, size_t n)
{
  for (size_t i = (size_t)blockIdx.x * 256 + threadIdx.x; i < n;
       i += (size_t)gridDim.x * 256)
    o[i] = (_Float16)in[i];
}

// ---------------------------------------------------------------------------
extern "C" void kernel_launch(void* const* d_in, const int* in_sizes, int n_in,
                              void* d_out, int out_size, void* d_ws, size_t ws_size,
                              hipStream_t stream)
{
  (void)in_sizes; (void)n_in; (void)out_size; (void)ws_size;
  const int*   ids = (const int*)  d_in[0];
  const float* emb = (const float*)d_in[1];
  const float* pos = (const float*)d_in[2];
  const float* kw  = (const float*)d_in[3];
  const float* cw  = (const float*)d_in[4];
  const float* cb  = (const float*)d_in[5];
  const float* w1  = (const float*)d_in[6];
  const float* b1  = (const float*)d_in[7];
  const float* w2  = (const float*)d_in[8];
  const float* b2  = (const float*)d_in[9];
  const float* nw  = (const float*)d_in[10];
  const float* pl  = (const float*)d_in[11];
  const float* fnw = (const float*)d_in[12];
  float* out = (float*)d_out;

  constexpr int B = 2, S = 1024, D = 1024, L = 8, V = 32000;
  constexpr int M = B * S;
  const size_t MN = (size_t)M * D;

  size_t off = 0;
  auto alloc = [&](size_t bytes) {
    char* p = (char*)d_ws + off;
    off += (bytes + 255) & ~(size_t)255;
    return (void*)p;
  };
  _Float16* kwT  = (_Float16*)alloc((size_t)L * 2 * D * D * 2);
  _Float16* w1T  = (_Float16*)alloc((size_t)L * 2 * D * D * 2);
  _Float16* w2T  = (_Float16*)alloc((size_t)L * 2 * D * D * 2);
  _Float16* plT  = (_Float16*)alloc((size_t)4 * D * D * 2);
  _Float16* emb16 = (_Float16*)alloc((size_t)V * D * 2);
  float* x    = (float*)alloc(MN * 4);
  _Float16* x16 = (_Float16*)alloc(MN * 2);
  _Float16* vaT16 = (_Float16*)alloc((size_t)M * 2 * D * 2);  // [2D][M] fp16
  _Float16* p16   = (_Float16*)alloc(2 * MN * 2);             // fp16 partials
  _Float16* z16 = (_Float16*)alloc(MN * 2);
  _Float16* u16 = (_Float16*)alloc((size_t)M * 2 * D * 2);
  _Float16* d16 = (_Float16*)alloc(MN * 2);
  _Float16* xf16 = (_Float16*)alloc(MN * 2);
  _Float16* lg16 = (_Float16*)alloc((size_t)M * V * 2);       // fp16 logits
  float* psum = (float*)alloc((size_t)M * (V >> 6) * 4);
  float* psq  = (float*)alloc((size_t)M * (V >> 6) * 4);

  const int PW = V >> 6;                 // 500

  {
    dim3 tb(32, 8);
    tsplit16<<<dim3(2 * D / 32, D / 32, L), tb, 0, stream>>>(kw, kwT, D, 2 * D);
    tsplit16<<<dim3(2 * D / 32, D / 32, L), tb, 0, stream>>>(w1, w1T, D, 2 * D);
    tsplit16<<<dim3(D / 32, 2 * D / 32, L), tb, 0, stream>>>(w2, w2T, 2 * D, D);
    tsplit16<<<dim3(D / 32, D / 32, 4),     tb, 0, stream>>>(pl, plT, D, D);
    cvt_f16<<<4096, 256, 0, stream>>>(emb, emb16, (size_t)V * D);
  }

  embed_norm<<<M, 256, 0, stream>>>(ids, emb, pos, x, x16, S, D);

  for (int i = 0; i < L; ++i) {
    const _Float16* kwi = kwT + (size_t)i * 2 * D * D;
    const _Float16* w1i = w1T + (size_t)i * 2 * D * D;
    const _Float16* w2i = w2T + (size_t)i * 2 * D * D;

    // G1: vaT16 = act(x@kw), channel-major fp16, fused tanh/sigm
    gemm16<1, 1><<<(M / 128) * (2 * D / 128), 512, 0, stream>>>(
        x16, kwi, M, 2 * D, D, nullptr, vaT16, nullptr, D);

    scanconv<<<B * D / 8, 256, 0, stream>>>(
        vaT16, cw + (size_t)i * D * 3, cb + (size_t)i * D, z16, S, D, M);

    // G2: u = silu(z@w1 + b1) -> fp16
    gemm16<2, 1><<<(M / 128) * (2 * D / 128), 512, 0, stream>>>(
        z16, w1i, M, 2 * D, D, nullptr, u16, b1 + (size_t)i * 2 * D, 0);

    // G3: hf partials (fp16) = u@w2 (split-K x2)
    gemm16<5, 2><<<(M / 128) * (D / 128) * 2, 512, 0, stream>>>(
        u16, w2i, M, D, 2 * D, nullptr, p16, nullptr, 0);

    const int mode = (i >= L - 4) ? 1 : 0;
    rms_fuse<<<M, 256, 0, stream>>>(p16, b2 + (size_t)i * D, nw + (size_t)i * D,
                                    x, mode ? d16 : x16, D, mode, MN);
    if (mode) {
      const _Float16* pli = plT + (size_t)(i - 4) * D * D;
      // G4: x += delta@plastic (direct accumulate, writes x16)
      gemm16<4, 1><<<(M / 128) * (D / 128), 512, 0, stream>>>(
          d16, pli, M, D, D, x, x16, nullptr, 0);
    }
  }

  final_norm<<<M, 256, 0, stream>>>(x, fnw, xf16, D);

  // LM head: fp16 logits to workspace + fused row stats
  gemm17h<<<(M / 256) * (V / 256), 512, 0, stream>>>(
      xf16, emb16, M, V, D, lg16, psum, psq);

  // scale+clip: fp16 logits -> fp32 d_out
  fix_row<<<M, 256, 0, stream>>>(lg16, out, psum, psq, PW, V);
}